// Round 7
// baseline (221.986 us; speedup 1.0000x reference)
//
#include <hip/hip_runtime.h>
#include <hip/hip_bf16.h>

#define BATCH 4
#define CDIM  256
#define NTOK  4096
#define THREE (3*CDIM)
#define VROWS 272   // 256 V channels + fg row at 256 (257..271 unused)

typedef unsigned short u16;
typedef __attribute__((ext_vector_type(4))) float f32x4;
typedef __attribute__((ext_vector_type(8))) short bf16x8;

#define AS1 __attribute__((address_space(1)))
#define AS3 __attribute__((address_space(3)))

__device__ __forceinline__ u16 f2bf(float x) {
  unsigned int u = __float_as_uint(x);
  unsigned int r = (u + 0x7fffu + ((u >> 16) & 1u)) >> 16;   // RTNE
  return (u16)r;
}
__device__ __forceinline__ float bf2f(u16 v) {
  return __uint_as_float(((unsigned int)v) << 16);
}

__device__ __forceinline__ void gload_lds16(const u16* g, u16* l) {
  __builtin_amdgcn_global_load_lds((AS1 const void*)g, (AS3 void*)l, 16, 0, 0);
}

// ---------------- K1: weights -> bf16; fg -> bf16 row in Vt ----------------
__global__ void k_prep(const float* __restrict__ Wqkv, const float* __restrict__ Wproj,
                       const int* __restrict__ fg,
                       u16* __restrict__ wq, u16* __restrict__ wp,
                       u16* __restrict__ Vt) {
  int i = blockIdx.x * 256 + threadIdx.x;
  const int nq = THREE * CDIM;          // 196608
  const int np = CDIM * CDIM;           // 65536
  const int nf = BATCH * NTOK;          // 16384 (fg row c=256)
  if (i < nq) { wq[i] = f2bf(Wqkv[i]); return; }
  int j = i - nq;
  if (j < np) { wp[j] = f2bf(Wproj[j]); return; }
  int k = j - np;
  if (k < nf) {
    int b = k >> 12, key = k & (NTOK - 1);
    Vt[((size_t)b * VROWS + 256) * NTOK + key] = fg[k] ? 0x3F80 : 0;  // bf16 1.0/0.0
  }
}

// ---------------- K2: x [B][C][N] f32 -> xbf [B][N][C] bf16 ----------------
__global__ __launch_bounds__(256) void k_transpose(const float* __restrict__ x, u16* __restrict__ xbf) {
  __shared__ u16 t[64][65];
  int n0 = blockIdx.x * 64;
  int c0 = blockIdx.y * 64;
  int b  = blockIdx.z;
  int tid = threadIdx.x;
  const float* xp = x + (size_t)b * CDIM * NTOK;
  int nl = tid & 63;
  int cb = tid >> 6;
#pragma unroll
  for (int i = 0; i < 16; ++i) {
    int cl = cb * 16 + i;
    t[nl][cl] = f2bf(xp[(size_t)(c0 + cl) * NTOK + n0 + nl]);
  }
  __syncthreads();
  int cl = tid & 63;
  int nb = tid >> 6;
  u16* op = xbf + ((size_t)b * NTOK + n0) * CDIM + c0;
#pragma unroll
  for (int i = 0; i < 16; ++i) {
    int nl2 = nb * 16 + i;
    op[(size_t)nl2 * CDIM + cl] = t[nl2][cl];
  }
}

// ---------------- K3: qkv GEMM. Q (x log2e/16), K row-major; V^T [c][key], fg-zeroed ----------------
__global__ __launch_bounds__(256) void k_qkv(const u16* __restrict__ xbf, const u16* __restrict__ wq,
                                             const int* __restrict__ fg,
                                             u16* __restrict__ Qm, u16* __restrict__ Km,
                                             u16* __restrict__ Vt) {
  __shared__ u16 Al[128][72];
  __shared__ u16 Bl[128][72];
  int n0 = blockIdx.x * 128;
  int d0 = blockIdx.y * 128;
  int b  = blockIdx.z;
  int tid = threadIdx.x;
  int lane = tid & 63, w = tid >> 6;
  int lo = lane & 15, hi = lane >> 4;
  int wm = w >> 1, wn = w & 1;
  f32x4 acc[4][4] = {};
  const u16* Ab = xbf + ((size_t)b * NTOK + n0) * CDIM;
  const u16* Bb = wq + (size_t)d0 * CDIM;
  for (int kc = 0; kc < 256; kc += 64) {
    __syncthreads();
#pragma unroll
    for (int i = 0; i < 4; ++i) {
      int cid = i * 256 + tid;
      int row = cid >> 3, cc = cid & 7;
      *(uint4*)&Al[row][cc * 8] = *(const uint4*)(Ab + (size_t)row * CDIM + kc + cc * 8);
      *(uint4*)&Bl[row][cc * 8] = *(const uint4*)(Bb + (size_t)row * CDIM + kc + cc * 8);
    }
    __syncthreads();
#pragma unroll
    for (int kk = 0; kk < 2; ++kk) {
      bf16x8 af[4], bfr[4];
#pragma unroll
      for (int mi = 0; mi < 4; ++mi) af[mi]  = *(const bf16x8*)&Al[wm * 64 + mi * 16 + lo][kk * 32 + hi * 8];
#pragma unroll
      for (int ni = 0; ni < 4; ++ni) bfr[ni] = *(const bf16x8*)&Bl[wn * 64 + ni * 16 + lo][kk * 32 + hi * 8];
#pragma unroll
      for (int mi = 0; mi < 4; ++mi)
#pragma unroll
        for (int ni = 0; ni < 4; ++ni)
          acc[mi][ni] = __builtin_amdgcn_mfma_f32_16x16x32_bf16(af[mi], bfr[ni], acc[mi][ni], 0, 0, 0);
    }
  }
  int seg = d0 >> 8;   // 0=Q 1=K 2=V
  const float QSC = 0.0625f * 1.4426950408889634f;   // (1/sqrt(C)) * log2(e)
#pragma unroll
  for (int mi = 0; mi < 4; ++mi) {
    int nbase = n0 + wm * 64 + mi * 16 + hi * 4;
#pragma unroll
    for (int ni = 0; ni < 4; ++ni) {
      int d = d0 + wn * 64 + ni * 16 + lo;
      if (seg == 0) {
#pragma unroll
        for (int r = 0; r < 4; ++r)
          Qm[((size_t)b * NTOK + nbase + r) * CDIM + d] = f2bf(acc[mi][ni][r] * QSC);
      } else if (seg == 1) {
        int dk = d - 256;
#pragma unroll
        for (int r = 0; r < 4; ++r)
          Km[((size_t)b * NTOK + nbase + r) * CDIM + dk] = f2bf(acc[mi][ni][r]);
      } else {
        int dv = d - 512;
        ushort4 pk;
        pk.x = fg[b * NTOK + nbase + 0] ? f2bf(acc[mi][ni][0]) : (u16)0;
        pk.y = fg[b * NTOK + nbase + 1] ? f2bf(acc[mi][ni][1]) : (u16)0;
        pk.z = fg[b * NTOK + nbase + 2] ? f2bf(acc[mi][ni][2]) : (u16)0;
        pk.w = fg[b * NTOK + nbase + 3] ? f2bf(acc[mi][ni][3]) : (u16)0;
        *(ushort4*)&Vt[((size_t)b * VROWS + dv) * NTOK + nbase] = pk;
      }
    }
  }
}

// ---------------- K4: flash attention, split-K, fixed-max, mask-in-V ----------------
// grid = 128*nsplit blocks; 4 waves x 32 q-rows; KBLK=32; double-buffered staging,
// static buffer pointers (manual unroll-2). P = exp2(QK - 12); numerator mask via
// zeroed V rows; l = sum P*fg via VALU FMA with the bf16 fg row as multiplier.
__global__ __launch_bounds__(256, 2) void k_attn(const u16* __restrict__ Qm, const u16* __restrict__ Km,
                                                 const u16* __restrict__ Vt,
                                                 u16* __restrict__ pacc, float2* __restrict__ pml,
                                                 int lsplit) {
  __shared__ u16 Kl[2][32 * 256];    // 16KB x2; row=512B, 16B-chunk ^= (row&7)<<4
  __shared__ u16 Vl[2][256 * 32];    // 16KB x2; row=64B (V^T [c][key]), chunk ^= row&3
  __shared__ u16 Pl[4][32 * 32];     // 2KB/wave; row=64B (P [q][key]), 16B-chunk ^= (q&12)<<2
  const float FM = 12.0f;            // fixed softmax max (log2 units), folded into sv init
  int nwg = gridDim.x;
  int cpx = nwg >> 3;
  int orig = blockIdx.x;
  int wg = (orig & 7) * cpx + (orig >> 3);   // bijective XCD swizzle (nwg % 8 == 0)
  int qt = wg & 31;
  int bs = wg >> 5;
  int s_k = bs & ((1 << lsplit) - 1);
  int b   = bs >> lsplit;
  int chunk = NTOK >> lsplit;
  int koff  = s_k * chunk;
  int iters = chunk >> 5;            // always even (8/16/32)

  int tid = threadIdx.x;
  int lane = tid & 63, w = tid >> 6;
  int lo = lane & 15, hi = lane >> 4;
  int n0 = qt * 128 + w * 32;
  // Q: 32 rows x 256 in registers (64 VGPR)
  bf16x8 qf[2][8];
#pragma unroll
  for (int s = 0; s < 2; ++s) {
    const u16* qp = Qm + ((size_t)b * NTOK + n0 + s * 16 + lo) * CDIM + hi * 8;
#pragma unroll
    for (int ks = 0; ks < 8; ++ks) qf[s][ks] = *(const bf16x8*)(qp + ks * 32);
  }
  f32x4 acc[2][16] = {};
  float lsum[2][4] = {};
  const u16* kbase = Km + (size_t)b * NTOK * CDIM;
  const u16* vbase = Vt + (size_t)b * VROWS * NTOK;
  const u16* fgrow = vbase + (size_t)256 * NTOK;   // bf16 fg multiplier row
  int kc  = lane & 31;   // K staging: 16B chunk within row pair
  int krp = lane >> 5;
  int vr  = lane >> 2;   // V staging: row within 16-row tile
  int vc  = lane & 3;

  // stage K (4 insts/wave) + V (4 insts/wave) for key-block m0
  auto stage = [&](u16* Kb, u16* Vb, int m0) {
    u16* kld = Kb + w * 2048;
#pragma unroll
    for (int j = 0; j < 4; ++j) {
      int row = w * 8 + j * 2 + krp;
      int sb = (kc * 16) ^ ((row & 7) << 4);
      gload_lds16(kbase + (size_t)(m0 + row) * CDIM + (sb >> 1), kld + j * 512);
    }
#pragma unroll
    for (int j = 0; j < 4; ++j) {
      int idx = j * 4 + w;                 // 0..15 tiles of 16 rows
      int r = idx * 16 + vr;
      int d = vc ^ (r & 3);
      gload_lds16(vbase + (size_t)r * NTOK + m0 + d * 8, Vb + idx * 512);
    }
  };

  // one iteration with compile-time buffer pointers
  auto body = [&](int it, const u16* Kcur, u16* Knxt, const u16* Vcur, u16* Vnxt) {
    int m0 = koff + it * 32;
    if (it + 1 < iters) stage(Knxt, Vnxt, m0 + 32);   // prefetch next tile
    // S - FM = Q K^T - 12 (log2 domain)
    f32x4 sv[2][2];
#pragma unroll
    for (int s = 0; s < 2; ++s)
#pragma unroll
      for (int ni = 0; ni < 2; ++ni)
#pragma unroll
        for (int r = 0; r < 4; ++r) sv[s][ni][r] = -FM;
    __builtin_amdgcn_s_setprio(1);
#pragma unroll
    for (int ks = 0; ks < 8; ++ks) {
      bf16x8 kf[2];
#pragma unroll
      for (int ni = 0; ni < 2; ++ni) {
        int row = ni * 16 + lo;
        const char* kp = (const char*)Kcur + row * 512 + ((ks * 64 + hi * 16) ^ ((row & 7) << 4));
        kf[ni] = *(const bf16x8*)kp;
      }
#pragma unroll
      for (int s = 0; s < 2; ++s)
#pragma unroll
        for (int ni = 0; ni < 2; ++ni)
          sv[s][ni] = __builtin_amdgcn_mfma_f32_16x16x32_bf16(qf[s][ks], kf[ni], sv[s][ni], 0, 0, 0);
    }
    __builtin_amdgcn_s_setprio(0);
    // P = exp2(S - FM); l += P * fg (VALU); P -> bf16 -> per-wave swizzled LDS
    float fgm[2];
    fgm[0] = bf2f(fgrow[m0 + lo]);
    fgm[1] = bf2f(fgrow[m0 + 16 + lo]);
#pragma unroll
    for (int s = 0; s < 2; ++s)
#pragma unroll
      for (int ni = 0; ni < 2; ++ni)
#pragma unroll
        for (int r = 0; r < 4; ++r) {
          float e = exp2f(sv[s][ni][r]);
          lsum[s][r] += e * fgm[ni];
          int q = s * 16 + hi * 4 + r;
          int byteoff = q * 64 + ((ni * 32 + lo * 2) ^ ((q & 12) << 2));
          *(u16*)((char*)&Pl[w][0] + byteoff) = f2bf(e);
        }
    // PV: A from Pl (wave-private, DS wave-ordered), B from Vl
    bf16x8 pa[2];
#pragma unroll
    for (int s = 0; s < 2; ++s) {
      const char* pp = (const char*)&Pl[w][0] + (s * 16 + lo) * 64 + ((hi * 16) ^ ((lo & 12) << 2));
      pa[s] = *(const bf16x8*)pp;
    }
    __builtin_amdgcn_s_setprio(1);
#pragma unroll
    for (int cf = 0; cf < 16; ++cf) {
      const char* vp = (const char*)Vcur + (cf * 16 + lo) * 64 + ((hi ^ (lo & 3)) << 4);
      bf16x8 vb = *(const bf16x8*)vp;
#pragma unroll
      for (int s = 0; s < 2; ++s)
        acc[s][cf] = __builtin_amdgcn_mfma_f32_16x16x32_bf16(pa[s], vb, acc[s][cf], 0, 0, 0);
    }
    __builtin_amdgcn_s_setprio(0);
    __syncthreads();   // drains next-tile stage loads; all waves done with cur buffers
  };

  stage(&Kl[0][0], &Vl[0][0], koff);
  __syncthreads();   // implicit vmcnt(0) drain covers the gload_lds deposits
  for (int it = 0; it < iters; it += 2) {
    body(it,     &Kl[0][0], &Kl[1][0], &Vl[0][0], &Vl[1][0]);
    body(it + 1, &Kl[1][0], &Kl[0][0], &Vl[1][0], &Vl[0][0]);
  }
  // one-time cross-lane l reduction (sum over the 16 lanes sharing hi)
  float ls[2][4];
#pragma unroll
  for (int s = 0; s < 2; ++s)
#pragma unroll
    for (int r = 0; r < 4; ++r) {
      float t = lsum[s][r];
      t += __shfl_xor(t, 1); t += __shfl_xor(t, 2);
      t += __shfl_xor(t, 4); t += __shfl_xor(t, 8);
      ls[s][r] = t;
    }
  // epilogue: bf16 unnormalized partials + (m=FM, l) per row
  u16* pb = pacc + (((size_t)s_k * BATCH + b) * NTOK + n0) * CDIM;
  float2* pm = pml + ((size_t)s_k * BATCH + b) * NTOK + n0;
#pragma unroll
  for (int s = 0; s < 2; ++s)
#pragma unroll
    for (int r = 0; r < 4; ++r) {
      int row = s * 16 + hi * 4 + r;
#pragma unroll
      for (int cf = 0; cf < 16; ++cf)
        pb[(size_t)row * CDIM + cf * 16 + lo] = f2bf(acc[s][cf][r]);
      if (lo == 0) {
        float2 v; v.x = FM; v.y = ls[s][r];
        pm[row] = v;
      }
    }
}

// ---------------- K4b: combine split-K partials -> h bf16 ----------------
__global__ __launch_bounds__(256) void k_comb(const u16* __restrict__ pacc,
                                              const float2* __restrict__ pml,
                                              u16* __restrict__ hbuf, int nsplit) {
  __shared__ float wgt[4][16];
  const int RN = BATCH * NTOK;
  int rbase = blockIdx.x * 16, t = threadIdx.x;
  if (t < 16) {
    int row = rbase + t;
    float m[4], l[4];
    float M = -3e38f;
#pragma unroll
    for (int s = 0; s < 4; ++s) if (s < nsplit) {
      float2 v = pml[(size_t)s * RN + row];
      m[s] = v.x; l[s] = v.y;
      M = fmaxf(M, m[s]);
    }
    float denom = 0.0f;
#pragma unroll
    for (int s = 0; s < 4; ++s) if (s < nsplit) {
      float wv = exp2f(m[s] - M);     // log2 domain
      m[s] = wv;
      denom += l[s] * wv;
    }
    float inv = 1.0f / denom;
#pragma unroll
    for (int s = 0; s < 4; ++s) if (s < nsplit) wgt[s][t] = m[s] * inv;
  }
  __syncthreads();
#pragma unroll 4
  for (int rr = 0; rr < 16; ++rr) {
    size_t row = rbase + rr;
    float h = 0.0f;
#pragma unroll
    for (int s = 0; s < 4; ++s) if (s < nsplit)
      h += bf2f(pacc[((size_t)s * RN + row) * CDIM + t]) * wgt[s][rr];
    hbuf[row * CDIM + t] = f2bf(h);
  }
}

// ---------------- K5: out[b][c][n] = b_proj[c] + sum_k h[b][n][k] Wp[c][k] ----------------
__global__ __launch_bounds__(256) void k_proj(const u16* __restrict__ hbuf, const u16* __restrict__ wp,
                                              const float* __restrict__ bproj, float* __restrict__ out) {
  __shared__ u16 Al[128][72];
  __shared__ u16 Bl[128][72];
  int n0 = blockIdx.x * 128;
  int c0 = blockIdx.y * 128;
  int b  = blockIdx.z;
  int tid = threadIdx.x;
  int lane = tid & 63, w = tid >> 6;
  int lo = lane & 15, hi = lane >> 4;
  int wm = w >> 1, wn = w & 1;
  f32x4 acc[4][4] = {};
  const u16* Ab = wp + (size_t)c0 * CDIM;
  const u16* Bb = hbuf + ((size_t)b * NTOK + n0) * CDIM;
  for (int kc = 0; kc < 256; kc += 64) {
    __syncthreads();
#pragma unroll
    for (int i = 0; i < 4; ++i) {
      int cid = i * 256 + tid;
      int row = cid >> 3, cc = cid & 7;
      *(uint4*)&Al[row][cc * 8] = *(const uint4*)(Ab + (size_t)row * CDIM + kc + cc * 8);
      *(uint4*)&Bl[row][cc * 8] = *(const uint4*)(Bb + (size_t)row * CDIM + kc + cc * 8);
    }
    __syncthreads();
#pragma unroll
    for (int kk = 0; kk < 2; ++kk) {
      bf16x8 af[4], bfr[4];
#pragma unroll
      for (int mi = 0; mi < 4; ++mi) af[mi]  = *(const bf16x8*)&Al[wm * 64 + mi * 16 + lo][kk * 32 + hi * 8];
#pragma unroll
      for (int ni = 0; ni < 4; ++ni) bfr[ni] = *(const bf16x8*)&Bl[wn * 64 + ni * 16 + lo][kk * 32 + hi * 8];
#pragma unroll
      for (int mi = 0; mi < 4; ++mi)
#pragma unroll
        for (int ni = 0; ni < 4; ++ni)
          acc[mi][ni] = __builtin_amdgcn_mfma_f32_16x16x32_bf16(af[mi], bfr[ni], acc[mi][ni], 0, 0, 0);
    }
  }
#pragma unroll
  for (int mi = 0; mi < 4; ++mi) {
    int cbase = c0 + wm * 64 + mi * 16 + hi * 4;
#pragma unroll
    for (int r = 0; r < 4; ++r) {
      float bias = bproj[cbase + r];
#pragma unroll
      for (int ni = 0; ni < 4; ++ni) {
        int n = n0 + wn * 64 + ni * 16 + lo;
        out[((size_t)b * CDIM + cbase + r) * NTOK + n] = acc[mi][ni][r] + bias;
      }
    }
  }
}

extern "C" void kernel_launch(void* const* d_in, const int* in_sizes, int n_in,
                              void* d_out, int out_size, void* d_ws, size_t ws_size,
                              hipStream_t stream) {
  const float* x     = (const float*)d_in[0];
  const int*   fg    = (const int*)d_in[1];
  const float* Wqkv  = (const float*)d_in[2];
  const float* Wproj = (const float*)d_in[3];
  const float* bproj = (const float*)d_in[4];
  float* out = (float*)d_out;
  char* ws = (char*)d_ws;
  u16*   xbf  = (u16*)(ws);                    // 8388608 B (also hbuf)
  u16*   Qm   = (u16*)(ws + 8388608);          // 8388608
  u16*   Km   = (u16*)(ws + 16777216);         // 8388608
  u16*   Vt   = (u16*)(ws + 25165824);         // 4*272*4096*2 = 8912896
  u16*   wq   = (u16*)(ws + 34078720);         // 393216
  u16*   wp   = (u16*)(ws + 34471936);         // 131072  -> ends 34603008
  u16*   hbuf = xbf;

  const size_t base = 34603008;
  const size_t per_acc = (size_t)BATCH * NTOK * CDIM * 2;   // 8 MiB per split (bf16)
  const size_t per_ml  = (size_t)BATCH * NTOK * 8;          // 128 KiB per split
  int nsplit = 4, lsplit = 2;
  if (base + 4 * (per_acc + per_ml) > ws_size) { nsplit = 2; lsplit = 1; }
  if (base + 2 * (per_acc + per_ml) > ws_size) { nsplit = 1; lsplit = 0; }
  u16*    pacc = (u16*)(ws + base);
  float2* pml  = (float2*)(ws + base + (size_t)nsplit * per_acc);

  k_prep<<<1088, 256, 0, stream>>>(Wqkv, Wproj, fg, wq, wp, Vt);
  k_transpose<<<dim3(64, 4, 4), 256, 0, stream>>>(x, xbf);
  k_qkv<<<dim3(32, 6, 4), 256, 0, stream>>>(xbf, wq, fg, Qm, Km, Vt);
  k_attn<<<128 * nsplit, 256, 0, stream>>>(Qm, Km, Vt, pacc, pml, lsplit);
  k_comb<<<1024, 256, 0, stream>>>(pacc, pml, hbuf, nsplit);
  k_proj<<<dim3(32, 2, 4), 256, 0, stream>>>(hbuf, wp, bproj, out);
}

// Round 8
// 198.723 us; speedup vs baseline: 1.1171x; 1.1171x over previous
//
#include <hip/hip_runtime.h>
#include <hip/hip_bf16.h>

#define BATCH 4
#define CDIM  256
#define NTOK  4096
#define THREE (3*CDIM)
#define VROWS 272   // 256 V channels + fg row at 256 (257..271 unused)

typedef unsigned short u16;
typedef __attribute__((ext_vector_type(4))) float f32x4;
typedef __attribute__((ext_vector_type(8))) short bf16x8;

#define AS1 __attribute__((address_space(1)))
#define AS3 __attribute__((address_space(3)))

__device__ __forceinline__ u16 f2bf(float x) {
  unsigned int u = __float_as_uint(x);
  unsigned int r = (u + 0x7fffu + ((u >> 16) & 1u)) >> 16;   // RTNE
  return (u16)r;
}
__device__ __forceinline__ float bf2f(u16 v) {
  return __uint_as_float(((unsigned int)v) << 16);
}

__device__ __forceinline__ void gload_lds16(const u16* g, u16* l) {
  __builtin_amdgcn_global_load_lds((AS1 const void*)g, (AS3 void*)l, 16, 0, 0);
}

// ---------------- K1: weights -> bf16; fg -> bf16 row in Vt ----------------
__global__ void k_prep(const float* __restrict__ Wqkv, const float* __restrict__ Wproj,
                       const int* __restrict__ fg,
                       u16* __restrict__ wq, u16* __restrict__ wp,
                       u16* __restrict__ Vt) {
  int i = blockIdx.x * 256 + threadIdx.x;
  const int nq = THREE * CDIM;          // 196608
  const int np = CDIM * CDIM;           // 65536
  const int nf = BATCH * NTOK;          // 16384 (fg row c=256)
  if (i < nq) { wq[i] = f2bf(Wqkv[i]); return; }
  int j = i - nq;
  if (j < np) { wp[j] = f2bf(Wproj[j]); return; }
  int k = j - np;
  if (k < nf) {
    int b = k >> 12, key = k & (NTOK - 1);
    Vt[((size_t)b * VROWS + 256) * NTOK + key] = fg[k] ? 0x3F80 : 0;  // bf16 1.0/0.0
  }
}

// ---------------- K2: x [B][C][N] f32 -> xbf [B][N][C] bf16 ----------------
__global__ __launch_bounds__(256) void k_transpose(const float* __restrict__ x, u16* __restrict__ xbf) {
  __shared__ u16 t[64][65];
  int n0 = blockIdx.x * 64;
  int c0 = blockIdx.y * 64;
  int b  = blockIdx.z;
  int tid = threadIdx.x;
  const float* xp = x + (size_t)b * CDIM * NTOK;
  int nl = tid & 63;
  int cb = tid >> 6;
#pragma unroll
  for (int i = 0; i < 16; ++i) {
    int cl = cb * 16 + i;
    t[nl][cl] = f2bf(xp[(size_t)(c0 + cl) * NTOK + n0 + nl]);
  }
  __syncthreads();
  int cl = tid & 63;
  int nb = tid >> 6;
  u16* op = xbf + ((size_t)b * NTOK + n0) * CDIM + c0;
#pragma unroll
  for (int i = 0; i < 16; ++i) {
    int nl2 = nb * 16 + i;
    op[(size_t)nl2 * CDIM + cl] = t[nl2][cl];
  }
}

// ---------------- K3: qkv GEMM. Q (x log2e/16), K row-major; V^T [c][key], fg-zeroed ----------------
__global__ __launch_bounds__(256) void k_qkv(const u16* __restrict__ xbf, const u16* __restrict__ wq,
                                             const int* __restrict__ fg,
                                             u16* __restrict__ Qm, u16* __restrict__ Km,
                                             u16* __restrict__ Vt) {
  __shared__ u16 Al[128][72];
  __shared__ u16 Bl[128][72];
  int n0 = blockIdx.x * 128;
  int d0 = blockIdx.y * 128;
  int b  = blockIdx.z;
  int tid = threadIdx.x;
  int lane = tid & 63, w = tid >> 6;
  int lo = lane & 15, hi = lane >> 4;
  int wm = w >> 1, wn = w & 1;
  f32x4 acc[4][4] = {};
  const u16* Ab = xbf + ((size_t)b * NTOK + n0) * CDIM;
  const u16* Bb = wq + (size_t)d0 * CDIM;
  for (int kc = 0; kc < 256; kc += 64) {
    __syncthreads();
#pragma unroll
    for (int i = 0; i < 4; ++i) {
      int cid = i * 256 + tid;
      int row = cid >> 3, cc = cid & 7;
      *(uint4*)&Al[row][cc * 8] = *(const uint4*)(Ab + (size_t)row * CDIM + kc + cc * 8);
      *(uint4*)&Bl[row][cc * 8] = *(const uint4*)(Bb + (size_t)row * CDIM + kc + cc * 8);
    }
    __syncthreads();
#pragma unroll
    for (int kk = 0; kk < 2; ++kk) {
      bf16x8 af[4], bfr[4];
#pragma unroll
      for (int mi = 0; mi < 4; ++mi) af[mi]  = *(const bf16x8*)&Al[wm * 64 + mi * 16 + lo][kk * 32 + hi * 8];
#pragma unroll
      for (int ni = 0; ni < 4; ++ni) bfr[ni] = *(const bf16x8*)&Bl[wn * 64 + ni * 16 + lo][kk * 32 + hi * 8];
#pragma unroll
      for (int mi = 0; mi < 4; ++mi)
#pragma unroll
        for (int ni = 0; ni < 4; ++ni)
          acc[mi][ni] = __builtin_amdgcn_mfma_f32_16x16x32_bf16(af[mi], bfr[ni], acc[mi][ni], 0, 0, 0);
    }
  }
  int seg = d0 >> 8;   // 0=Q 1=K 2=V
  const float QSC = 0.0625f * 1.4426950408889634f;   // (1/sqrt(C)) * log2(e)
#pragma unroll
  for (int mi = 0; mi < 4; ++mi) {
    int nbase = n0 + wm * 64 + mi * 16 + hi * 4;
#pragma unroll
    for (int ni = 0; ni < 4; ++ni) {
      int d = d0 + wn * 64 + ni * 16 + lo;
      if (seg == 0) {
#pragma unroll
        for (int r = 0; r < 4; ++r)
          Qm[((size_t)b * NTOK + nbase + r) * CDIM + d] = f2bf(acc[mi][ni][r] * QSC);
      } else if (seg == 1) {
        int dk = d - 256;
#pragma unroll
        for (int r = 0; r < 4; ++r)
          Km[((size_t)b * NTOK + nbase + r) * CDIM + dk] = f2bf(acc[mi][ni][r]);
      } else {
        int dv = d - 512;
        ushort4 pk;
        pk.x = fg[b * NTOK + nbase + 0] ? f2bf(acc[mi][ni][0]) : (u16)0;
        pk.y = fg[b * NTOK + nbase + 1] ? f2bf(acc[mi][ni][1]) : (u16)0;
        pk.z = fg[b * NTOK + nbase + 2] ? f2bf(acc[mi][ni][2]) : (u16)0;
        pk.w = fg[b * NTOK + nbase + 3] ? f2bf(acc[mi][ni][3]) : (u16)0;
        *(ushort4*)&Vt[((size_t)b * VROWS + dv) * NTOK + nbase] = pk;
      }
    }
  }
}

// ---------------- K4: flash attention, split-K(4), fixed-max, mask-in-V ----------------
// grid = 512 blocks; 4 waves x 32 q-rows; KBLK=32; double-buffered staging with
// COUNTED vmcnt (8 loads/wave/tile, 2 tiles in flight) + raw barriers — no full drain.
// P = exp2(QK - 12); numerator mask via zeroed V rows; l = sum P*fg with the bf16 fg
// row staged in LDS (no mid-loop global loads).
__global__ __launch_bounds__(256, 2) void k_attn(const u16* __restrict__ Qm, const u16* __restrict__ Km,
                                                 const u16* __restrict__ Vt,
                                                 u16* __restrict__ pacc, float2* __restrict__ pml) {
  __shared__ u16 Kl[2][32 * 256];    // 16KB x2; row=512B, 16B-chunk ^= (row&7)<<4
  __shared__ u16 Vl[2][256 * 32];    // 16KB x2; row=64B (V^T [c][key]), chunk ^= row&3
  __shared__ u16 Pl[4][32 * 32];     // 2KB/wave; row=64B (P [q][key]), 16B-chunk ^= (q&12)<<2
  __shared__ u16 fgl[1024];          // bf16 fg for this chunk's 1024 keys
  const float FM = 12.0f;            // fixed softmax max (log2 units)
  const int LSPLIT = 2;
  int nwg = gridDim.x;
  int cpx = nwg >> 3;
  int orig = blockIdx.x;
  int wg = (orig & 7) * cpx + (orig >> 3);   // bijective XCD swizzle (nwg % 8 == 0)
  int qt = wg & 31;
  int bs = wg >> 5;
  int s_k = bs & 3;
  int b   = bs >> LSPLIT;
  const int chunk = NTOK >> LSPLIT;          // 1024
  int koff  = s_k * chunk;
  const int iters = chunk >> 5;              // 32

  int tid = threadIdx.x;
  int lane = tid & 63, w = tid >> 6;
  int lo = lane & 15, hi = lane >> 4;
  int n0 = qt * 128 + w * 32;
  // Q: 32 rows x 256 in registers (64 VGPR)
  bf16x8 qf[2][8];
#pragma unroll
  for (int s = 0; s < 2; ++s) {
    const u16* qp = Qm + ((size_t)b * NTOK + n0 + s * 16 + lo) * CDIM + hi * 8;
#pragma unroll
    for (int ks = 0; ks < 8; ++ks) qf[s][ks] = *(const bf16x8*)(qp + ks * 32);
  }
  f32x4 acc[2][16] = {};
  float lsum[2][4] = {};
  const u16* kbase = Km + (size_t)b * NTOK * CDIM;
  const u16* vbase = Vt + (size_t)b * VROWS * NTOK;
  const u16* fgrow = vbase + (size_t)256 * NTOK;   // bf16 fg row
  int kc  = lane & 31;   // K staging: 16B chunk within row pair
  int krp = lane >> 5;
  int vr  = lane >> 2;   // V staging: row within 16-row tile
  int vc  = lane & 3;

  // stage K (4 insts/wave) + V (4 insts/wave) for key-block m0 — 8 loads/wave, uniform
  auto stage = [&](u16* Kb, u16* Vb, int m0) {
    u16* kld = Kb + w * 2048;
#pragma unroll
    for (int j = 0; j < 4; ++j) {
      int row = w * 8 + j * 2 + krp;
      int sb = (kc * 16) ^ ((row & 7) << 4);
      gload_lds16(kbase + (size_t)(m0 + row) * CDIM + (sb >> 1), kld + j * 512);
    }
#pragma unroll
    for (int j = 0; j < 4; ++j) {
      int idx = j * 4 + w;                 // 0..15 tiles of 16 rows
      int r = idx * 16 + vr;
      int d = vc ^ (r & 3);
      gload_lds16(vbase + (size_t)r * NTOK + m0 + d * 8, Vb + idx * 512);
    }
  };

  // one iteration; tile `it` already resident after vmcnt+barrier
  auto body = [&](int it, const u16* Kcur, const u16* Vcur, u16* Kst, u16* Vst, bool last) {
    if (last) asm volatile("s_waitcnt vmcnt(0)" ::: "memory");
    else      asm volatile("s_waitcnt vmcnt(8)" ::: "memory");
    __builtin_amdgcn_s_barrier();        // all waves: tile it fully resident
    int m0 = koff + it * 32;
    // S - FM = Q K^T - 12 (log2 domain)
    f32x4 sv[2][2];
#pragma unroll
    for (int s = 0; s < 2; ++s)
#pragma unroll
      for (int ni = 0; ni < 2; ++ni)
#pragma unroll
        for (int r = 0; r < 4; ++r) sv[s][ni][r] = -FM;
    __builtin_amdgcn_s_setprio(1);
#pragma unroll
    for (int ks = 0; ks < 8; ++ks) {
      bf16x8 kf[2];
#pragma unroll
      for (int ni = 0; ni < 2; ++ni) {
        int row = ni * 16 + lo;
        const char* kp = (const char*)Kcur + row * 512 + ((ks * 64 + hi * 16) ^ ((row & 7) << 4));
        kf[ni] = *(const bf16x8*)kp;
      }
#pragma unroll
      for (int s = 0; s < 2; ++s)
#pragma unroll
        for (int ni = 0; ni < 2; ++ni)
          sv[s][ni] = __builtin_amdgcn_mfma_f32_16x16x32_bf16(qf[s][ks], kf[ni], sv[s][ni], 0, 0, 0);
    }
    __builtin_amdgcn_s_setprio(0);
    // P = exp2(S-FM); l += P * fg (fg from LDS); P -> bf16 -> per-wave swizzled LDS
    float fgm[2];
    fgm[0] = bf2f(fgl[it * 32 + lo]);
    fgm[1] = bf2f(fgl[it * 32 + 16 + lo]);
#pragma unroll
    for (int s = 0; s < 2; ++s)
#pragma unroll
      for (int ni = 0; ni < 2; ++ni)
#pragma unroll
        for (int r = 0; r < 4; ++r) {
          float e = exp2f(sv[s][ni][r]);
          lsum[s][r] += e * fgm[ni];
          int q = s * 16 + hi * 4 + r;
          int byteoff = q * 64 + ((ni * 32 + lo * 2) ^ ((q & 12) << 2));
          *(u16*)((char*)&Pl[w][0] + byteoff) = f2bf(e);
        }
    // PV: A from Pl (wave-private, DS wave-ordered), B from Vl
    bf16x8 pa[2];
#pragma unroll
    for (int s = 0; s < 2; ++s) {
      const char* pp = (const char*)&Pl[w][0] + (s * 16 + lo) * 64 + ((hi * 16) ^ ((lo & 12) << 2));
      pa[s] = *(const bf16x8*)pp;
    }
    __builtin_amdgcn_s_setprio(1);
#pragma unroll
    for (int cf = 0; cf < 16; ++cf) {
      const char* vp = (const char*)Vcur + (cf * 16 + lo) * 64 + ((hi ^ (lo & 3)) << 4);
      bf16x8 vb = *(const bf16x8*)vp;
#pragma unroll
      for (int s = 0; s < 2; ++s)
        acc[s][cf] = __builtin_amdgcn_mfma_f32_16x16x32_bf16(pa[s], vb, acc[s][cf], 0, 0, 0);
    }
    __builtin_amdgcn_s_setprio(0);
    __builtin_amdgcn_s_barrier();        // all waves done reading cur buffers
    if (it + 2 < iters) stage(Kst, Vst, m0 + 64);   // refill freed buffers (counted, no drain)
  };

  // prologue: fg chunk (w<2: 1 extra load) + tiles 0,1
  if (w < 2) gload_lds16(fgrow + koff + w * 512 + lane * 8, &fgl[w * 512 + lane * 8]);
  stage(&Kl[0][0], &Vl[0][0], koff);
  stage(&Kl[1][0], &Vl[1][0], koff + 32);
  for (int it = 0; it < iters; it += 2) {
    body(it,     &Kl[0][0], &Vl[0][0], &Kl[0][0], &Vl[0][0], false);
    body(it + 1, &Kl[1][0], &Vl[1][0], &Kl[1][0], &Vl[1][0], it + 1 == iters - 1);
  }
  // one-time cross-lane l reduction (sum over the 16 lanes sharing hi)
  float ls[2][4];
#pragma unroll
  for (int s = 0; s < 2; ++s)
#pragma unroll
    for (int r = 0; r < 4; ++r) {
      float t = lsum[s][r];
      t += __shfl_xor(t, 1); t += __shfl_xor(t, 2);
      t += __shfl_xor(t, 4); t += __shfl_xor(t, 8);
      ls[s][r] = t;
    }
  // epilogue: bf16 unnormalized partials + (m=FM, l) per row
  u16* pb = pacc + (((size_t)s_k * BATCH + b) * NTOK + n0) * CDIM;
  float2* pm = pml + ((size_t)s_k * BATCH + b) * NTOK + n0;
#pragma unroll
  for (int s = 0; s < 2; ++s)
#pragma unroll
    for (int r = 0; r < 4; ++r) {
      int row = s * 16 + hi * 4 + r;
#pragma unroll
      for (int cf = 0; cf < 16; ++cf)
        pb[(size_t)row * CDIM + cf * 16 + lo] = f2bf(acc[s][cf][r]);
      if (lo == 0) {
        float2 v; v.x = FM; v.y = ls[s][r];
        pm[row] = v;
      }
    }
}

// ---------------- K4b: combine split-K(4) partials -> h bf16 ----------------
__global__ __launch_bounds__(256) void k_comb(const u16* __restrict__ pacc,
                                              const float2* __restrict__ pml,
                                              u16* __restrict__ hbuf) {
  __shared__ float wgt[4][16];
  const int RN = BATCH * NTOK;
  int rbase = blockIdx.x * 16, t = threadIdx.x;
  if (t < 16) {
    int row = rbase + t;
    float denom = 0.0f;
#pragma unroll
    for (int s = 0; s < 4; ++s) denom += pml[(size_t)s * RN + row].y;  // all m == FM
    float inv = 1.0f / denom;
#pragma unroll
    for (int s = 0; s < 4; ++s) wgt[s][t] = inv;
  }
  __syncthreads();
#pragma unroll 4
  for (int rr = 0; rr < 16; ++rr) {
    size_t row = rbase + rr;
    float h = 0.0f;
#pragma unroll
    for (int s = 0; s < 4; ++s)
      h += bf2f(pacc[((size_t)s * RN + row) * CDIM + t]);
    hbuf[row * CDIM + t] = f2bf(h * wgt[0][rr]);
  }
}

// ---------------- K5: out[b][c][n] = b_proj[c] + sum_k h[b][n][k] Wp[c][k] ----------------
__global__ __launch_bounds__(256) void k_proj(const u16* __restrict__ hbuf, const u16* __restrict__ wp,
                                              const float* __restrict__ bproj, float* __restrict__ out) {
  __shared__ u16 Al[128][72];
  __shared__ u16 Bl[128][72];
  int n0 = blockIdx.x * 128;
  int c0 = blockIdx.y * 128;
  int b  = blockIdx.z;
  int tid = threadIdx.x;
  int lane = tid & 63, w = tid >> 6;
  int lo = lane & 15, hi = lane >> 4;
  int wm = w >> 1, wn = w & 1;
  f32x4 acc[4][4] = {};
  const u16* Ab = wp + (size_t)c0 * CDIM;
  const u16* Bb = hbuf + ((size_t)b * NTOK + n0) * CDIM;
  for (int kc = 0; kc < 256; kc += 64) {
    __syncthreads();
#pragma unroll
    for (int i = 0; i < 4; ++i) {
      int cid = i * 256 + tid;
      int row = cid >> 3, cc = cid & 7;
      *(uint4*)&Al[row][cc * 8] = *(const uint4*)(Ab + (size_t)row * CDIM + kc + cc * 8);
      *(uint4*)&Bl[row][cc * 8] = *(const uint4*)(Bb + (size_t)row * CDIM + kc + cc * 8);
    }
    __syncthreads();
#pragma unroll
    for (int kk = 0; kk < 2; ++kk) {
      bf16x8 af[4], bfr[4];
#pragma unroll
      for (int mi = 0; mi < 4; ++mi) af[mi]  = *(const bf16x8*)&Al[wm * 64 + mi * 16 + lo][kk * 32 + hi * 8];
#pragma unroll
      for (int ni = 0; ni < 4; ++ni) bfr[ni] = *(const bf16x8*)&Bl[wn * 64 + ni * 16 + lo][kk * 32 + hi * 8];
#pragma unroll
      for (int mi = 0; mi < 4; ++mi)
#pragma unroll
        for (int ni = 0; ni < 4; ++ni)
          acc[mi][ni] = __builtin_amdgcn_mfma_f32_16x16x32_bf16(af[mi], bfr[ni], acc[mi][ni], 0, 0, 0);
    }
  }
#pragma unroll
  for (int mi = 0; mi < 4; ++mi) {
    int cbase = c0 + wm * 64 + mi * 16 + hi * 4;
#pragma unroll
    for (int r = 0; r < 4; ++r) {
      float bias = bproj[cbase + r];
#pragma unroll
      for (int ni = 0; ni < 4; ++ni) {
        int n = n0 + wn * 64 + ni * 16 + lo;
        out[((size_t)b * CDIM + cbase + r) * NTOK + n] = acc[mi][ni][r] + bias;
      }
    }
  }
}

extern "C" void kernel_launch(void* const* d_in, const int* in_sizes, int n_in,
                              void* d_out, int out_size, void* d_ws, size_t ws_size,
                              hipStream_t stream) {
  const float* x     = (const float*)d_in[0];
  const int*   fg    = (const int*)d_in[1];
  const float* Wqkv  = (const float*)d_in[2];
  const float* Wproj = (const float*)d_in[3];
  const float* bproj = (const float*)d_in[4];
  float* out = (float*)d_out;
  char* ws = (char*)d_ws;
  u16*   xbf  = (u16*)(ws);                    // 8388608 B (also hbuf)
  u16*   Qm   = (u16*)(ws + 8388608);          // 8388608
  u16*   Km   = (u16*)(ws + 16777216);         // 8388608
  u16*   Vt   = (u16*)(ws + 25165824);         // 4*272*4096*2 = 8912896
  u16*   wq   = (u16*)(ws + 34078720);         // 393216
  u16*   wp   = (u16*)(ws + 34471936);         // 131072  -> ends 34603008
  u16*   hbuf = xbf;

  const size_t base = 34603008;
  const size_t per_acc = (size_t)BATCH * NTOK * CDIM * 2;   // 8 MiB per split (bf16)
  u16*    pacc = (u16*)(ws + base);
  float2* pml  = (float2*)(ws + base + 4 * per_acc);        // 512 KiB

  k_prep<<<1088, 256, 0, stream>>>(Wqkv, Wproj, fg, wq, wp, Vt);
  k_transpose<<<dim3(64, 4, 4), 256, 0, stream>>>(x, xbf);
  k_qkv<<<dim3(32, 6, 4), 256, 0, stream>>>(xbf, wq, fg, Qm, Km, Vt);
  k_attn<<<512, 256, 0, stream>>>(Qm, Km, Vt, pacc, pml);
  k_comb<<<1024, 256, 0, stream>>>(pacc, pml, hbuf);
  k_proj<<<dim3(32, 2, 4), 256, 0, stream>>>(hbuf, wp, bproj, out);
}